// Round 19
// baseline (158.521 us; speedup 1.0000x reference)
//
#include <hip/hip_runtime.h>
#include <hip/hip_bf16.h>

typedef __bf16 bf16x8 __attribute__((ext_vector_type(8)));
typedef float f32x4 __attribute__((ext_vector_type(4)));
typedef unsigned short us8 __attribute__((ext_vector_type(8)));
typedef unsigned int u32x4 __attribute__((ext_vector_type(4)));

#define E_ 640
#define CD_ 768
#define B_ 32
#define SQ_ 1024
#define SKV_ 77
#define H_ 8
#define DH_ 80

typedef __attribute__((address_space(3))) unsigned int as3_u32;
typedef __attribute__((address_space(1))) const unsigned int as1_u32;

__device__ __forceinline__ void gload16(const unsigned short* g, unsigned short* l) {
    __builtin_amdgcn_global_load_lds((as1_u32*)g, (as3_u32*)l, 16, 0, 0);
}

__device__ __forceinline__ float b2f(unsigned short u) {
    unsigned int x = ((unsigned int)u) << 16;
    return __builtin_bit_cast(float, x);
}
__device__ __forceinline__ unsigned short f2b(float f) {
    unsigned int x = __builtin_bit_cast(unsigned int, f);
    x += 0x7fffu + ((x >> 16) & 1u);   // RNE
    return (unsigned short)(x >> 16);
}
__device__ __forceinline__ bf16x8 lv8(const unsigned short* p) {
    return __builtin_bit_cast(bf16x8, *reinterpret_cast<const us8*>(p));
}
__device__ __forceinline__ bf16x8 zero8() {
    us8 z = {0,0,0,0,0,0,0,0};
    return __builtin_bit_cast(bf16x8, z);
}
// 8 fp32 -> bf16x8 via v_cvt_pk_bf16_f32 (RNE)
__device__ __forceinline__ bf16x8 cvtpk8(f32x4 lo, f32x4 hi) {
    unsigned int w0, w1, w2, w3;
    asm("v_cvt_pk_bf16_f32 %0, %1, %2" : "=v"(w0) : "v"(lo[0]), "v"(lo[1]));
    asm("v_cvt_pk_bf16_f32 %0, %1, %2" : "=v"(w1) : "v"(lo[2]), "v"(lo[3]));
    asm("v_cvt_pk_bf16_f32 %0, %1, %2" : "=v"(w2) : "v"(hi[0]), "v"(hi[1]));
    asm("v_cvt_pk_bf16_f32 %0, %1, %2" : "=v"(w3) : "v"(hi[2]), "v"(hi[3]));
    u32x4 w = {w0, w1, w2, w3};
    return __builtin_bit_cast(bf16x8, w);
}
__device__ __forceinline__ us8 cvt8(const float* s) {
    f32x4 f0 = *reinterpret_cast<const f32x4*>(s);
    f32x4 f1 = *reinterpret_cast<const f32x4*>(s + 4);
    return __builtin_bit_cast(us8, cvtpk8(f0, f1));
}

// ---------------- fused prep: 4 weight transposes + x,y -> bf16 converts ----------------
__device__ __forceinline__ void transpose_body(
    const float* __restrict__ in, unsigned short* __restrict__ out,
    int K, int N, int bx, int by, unsigned short (*t)[33])
{
    const int tx = threadIdx.x & 31, ty = threadIdx.x >> 5;
    const int n0 = bx * 32, k0 = by * 32;
#pragma unroll
    for (int i = 0; i < 4; ++i)
        t[ty + 8*i][tx] = f2b(in[(size_t)(k0 + ty + 8*i) * N + n0 + tx]);
    __syncthreads();
#pragma unroll
    for (int i = 0; i < 4; ++i)
        out[(size_t)(n0 + ty + 8*i) * K + k0 + tx] = t[tx][ty + 8*i];
}

__global__ __launch_bounds__(256) void fused_prep(
    const float* __restrict__ Wq, unsigned short* __restrict__ WqT,
    const float* __restrict__ Wo, unsigned short* __restrict__ WoT,
    const float* __restrict__ Wk, unsigned short* __restrict__ WkT,
    const float* __restrict__ Wv, unsigned short* __restrict__ WvT,
    const float* __restrict__ x, unsigned short* __restrict__ Xb,
    const float* __restrict__ y, unsigned short* __restrict__ Yb)
{
    __shared__ unsigned short t[32][33];
    const int id = blockIdx.x;
    if (id < 800) {                         // Wq / Wo : [640][640]
        int z = id / 400, rem = id % 400;
        transpose_body(z ? Wo : Wq, z ? WoT : WqT, 640, 640, rem % 20, rem / 20, t);
    } else if (id < 1760) {                 // Wk / Wv : [768][640]
        int id2 = id - 800, z = id2 / 480, rem = id2 % 480;
        transpose_body(z ? Wv : Wk, z ? WvT : WkT, 768, 640, rem % 20, rem / 20, t);
    } else if (id < 3808) {                 // convert x: 2048 blocks, 2,621,440 x us8
        long i = (long)(id - 1760) * 256 + threadIdx.x;
        const long stride = 2048L * 256;
        for (const long n8 = 2621440L; i < n8; i += stride)
            *reinterpret_cast<us8*>(Xb + i * 8) = cvt8(x + i * 8);
    } else {                                // convert y: 240 blocks, 236,544 x us8
        long i = (long)(id - 3808) * 256 + threadIdx.x;
        const long stride = 240L * 256;
        for (const long n8 = 236544L; i < n8; i += stride)
            *reinterpret_cast<us8*>(Yb + i * 8) = cvt8(y + i * 8);
    }
}

// ======== pipelined 256x128 GEMM (bf16 A via global_load_lds, 512 threads) ========
// 8 waves (4x2), each computing 64x64. 2-buffer K-loop, T3-minimum schedule:
// per step { vmcnt(0); s_barrier; STAGE(t+1); COMPUTE(t) } — loads for t+1
// fly under COMPUTE(t). 48 KB LDS -> 3 blocks/CU.
// A rows [m0, m0+256) must be readable; C stores masked by grow < M.
template<bool CF32>
__device__ __forceinline__ void gemm_pipe(
    const unsigned short* __restrict__ A,
    const unsigned short* __restrict__ Wt,
    const float* __restrict__ bias,
    void* __restrict__ Cp,
    int M, int K, int ldc, int m0, int n0,
    unsigned short* smem)    // >= 24576 shorts (48 KB)
{
    const int tid = threadIdx.x, lane = tid & 63, wave = tid >> 6;
    const int wr = (wave >> 1) << 6;          // 0,64,128,192
    const int wc = (wave & 1) << 6;           // 0,64
    const int l15 = lane & 15, l4 = lane >> 4;
    const int sgz = (tid >> 3) & 3;
    const int srd = (l15 >> 1) & 3;
    const int rdo = (l4 ^ srd) << 3;

    const unsigned short* gW0 = Wt + (size_t)(n0 + (tid >> 2)) * K + (((tid & 3) ^ sgz) << 3);
    const unsigned short* gA0 = A + (size_t)(m0 + (tid >> 2)) * K + (((tid & 3) ^ sgz) << 3);
    const unsigned short* gA1 = A + (size_t)(m0 + (tid >> 2) + 128) * K + (((tid & 3) ^ sgz) << 3);

    f32x4 acc[4][4];
#pragma unroll
    for (int m = 0; m < 4; ++m)
#pragma unroll
        for (int n = 0; n < 4; ++n)
#pragma unroll
            for (int i = 0; i < 4; ++i) acc[m][n][i] = 0.f;

    auto STAGE = [&](int buf) {
        unsigned short* As = smem + buf * 12288;
        unsigned short* Ws = As + 8192;
        gload16(gA0, As + tid * 8);
        gload16(gA1, As + (tid + 512) * 8);
        gload16(gW0, Ws + tid * 8);
        gA0 += 32; gA1 += 32; gW0 += 32;
    };
    auto COMPUTE = [&](int buf) {
        const unsigned short* As = smem + buf * 12288;
        const unsigned short* Ws = As + 8192;
        bf16x8 a[4], b[4];
#pragma unroll
        for (int m = 0; m < 4; ++m)
            a[m] = lv8(&As[(wr + m * 16 + l15) * 32 + rdo]);
#pragma unroll
        for (int n = 0; n < 4; ++n)
            b[n] = lv8(&Ws[(wc + n * 16 + l15) * 32 + rdo]);
        __builtin_amdgcn_s_setprio(1);
#pragma unroll
        for (int m = 0; m < 4; ++m)
#pragma unroll
            for (int n = 0; n < 4; ++n)
                acc[m][n] = __builtin_amdgcn_mfma_f32_16x16x32_bf16(a[m], b[n], acc[m][n], 0, 0, 0);
        __builtin_amdgcn_s_setprio(0);
    };

    const int nk = K >> 5;   // 20 or 24
    STAGE(0);
    for (int t = 0; t < nk; ++t) {
        asm volatile("s_waitcnt vmcnt(0)" ::: "memory");
        __builtin_amdgcn_sched_barrier(0);
        __builtin_amdgcn_s_barrier();
        if (t + 1 < nk) STAGE((t + 1) & 1);
        COMPUTE(t & 1);
    }

    float bs[4];
#pragma unroll
    for (int n = 0; n < 4; ++n) bs[n] = bias[n0 + wc + n * 16 + l15];

    if constexpr (CF32) {
        // fp32 epilogue: four 64-row passes, 64x128 f32 tile (32 KB) in LDS
        float* C = (float*)Cp;
        float* fs = (float*)smem;
#pragma unroll
        for (int p = 0; p < 4; ++p) {
            __syncthreads();
            if ((wr >> 6) == p) {
#pragma unroll
                for (int m = 0; m < 4; ++m)
#pragma unroll
                    for (int n = 0; n < 4; ++n)
#pragma unroll
                        for (int i = 0; i < 4; ++i)
                            fs[(m * 16 + l4 * 4 + i) * 128 + wc + n * 16 + l15] =
                                acc[m][n][i] + bs[n];
            }
            __syncthreads();
#pragma unroll
            for (int r = 0; r < 4; ++r) {
                const int off = (r * 512 + tid) * 4;
                const int row = off >> 7, col = off & 127;
                const int grow = m0 + p * 64 + row;
                if (grow < M)
                    *reinterpret_cast<f32x4*>(&C[(size_t)grow * ldc + n0 + col]) =
                        *reinterpret_cast<const f32x4*>(&fs[off]);
            }
        }
    } else {
        // bf16 epilogue: two 128-row passes, 128x128 bf16 tile (32 KB) in LDS
        unsigned short* C = (unsigned short*)Cp;
#pragma unroll
        for (int p = 0; p < 2; ++p) {
            __syncthreads();
            if ((wr >> 7) == p) {
                const int lr0 = (wr & 64);
#pragma unroll
                for (int m = 0; m < 4; ++m)
#pragma unroll
                    for (int n = 0; n < 4; ++n)
#pragma unroll
                        for (int i = 0; i < 4; ++i)
                            smem[(lr0 + m * 16 + l4 * 4 + i) * 128 + wc + n * 16 + l15] =
                                f2b(acc[m][n][i] + bs[n]);
            }
            __syncthreads();
#pragma unroll
            for (int r = 0; r < 4; ++r) {
                const int off = (r * 512 + tid) * 8;
                const int row = off >> 7, col = off & 127;
                const int grow = m0 + p * 128 + row;
                if (grow < M)
                    *reinterpret_cast<us8*>(&C[(size_t)grow * ldc + n0 + col]) =
                        *reinterpret_cast<us8*>(&smem[off]);
            }
        }
    }
}

// ---------------- fused QKV: all three projections via 256x128 gemm_pipe ----------------
// blocks [0,50): K; [50,100): V (Yb padded to 2560 rows); [100,740): Q (XCD swizzle)
__global__ __launch_bounds__(512) void fused_qkv(
    const unsigned short* __restrict__ Xb, const unsigned short* __restrict__ WqT,
    const float* __restrict__ bq, unsigned short* __restrict__ Qb,
    const unsigned short* __restrict__ Yb,
    const unsigned short* __restrict__ WkT, const float* __restrict__ bk2, unsigned short* __restrict__ Kb,
    const unsigned short* __restrict__ WvT, const float* __restrict__ bv2, unsigned short* __restrict__ Vb)
{
    __shared__ __align__(16) unsigned short smem[24576];   // 48 KB
    const int id = blockIdx.x;
    if (id < 100) {
        int z = id / 50, rem = id % 50;
        int m0 = (rem / 5) * 256, n0 = (rem % 5) * 128;    // m0 up to 2304
        if (z == 0) gemm_pipe<false>(Yb, WkT, bk2, Kb, 2464, 768, 640, m0, n0, smem);
        else        gemm_pipe<false>(Yb, WvT, bv2, Vb, 2464, 768, 640, m0, n0, smem);
    } else {
        int orig = id - 100;                       // 0..639, 640 % 8 == 0
        int wgid = (orig & 7) * 80 + (orig >> 3);  // XCD-chunked bijection
        int m0 = (wgid / 5) * 256, n0 = (wgid % 5) * 128;
        gemm_pipe<false>(Xb, WqT, bq, Qb, 32768, 640, 640, m0, n0, smem);
    }
}

// ---------------- vtrans: Vb [32*77][640] -> Vt [b*8+h][80][80] (kv 77..79 zeroed) ----------------
__global__ __launch_bounds__(256) void vtrans_kernel(
    const unsigned short* __restrict__ Vb, unsigned short* __restrict__ Vt)
{
    __shared__ unsigned short Vl[77 * 88 + 8];
    const int r = blockIdx.x, b = r >> 3, h = r & 7;
    const int tid = threadIdx.x;
    for (int idx = tid; idx < 770; idx += 256) {
        int kv = idx / 10, seg = idx % 10;
        *reinterpret_cast<us8*>(&Vl[kv * 88 + seg * 8]) =
            *reinterpret_cast<const us8*>(&Vb[(size_t)(b * 77 + kv) * 640 + h * 80 + seg * 8]);
    }
    __syncthreads();
    unsigned short* out = Vt + (size_t)(b * 8 + h) * 6400;
    for (int idx = tid; idx < 800; idx += 256) {
        int d = idx / 10, seg = idx % 10;
        us8 v;
#pragma unroll
        for (int j = 0; j < 8; ++j) {
            int kv = seg * 8 + j;
            v[j] = (kv < 77) ? Vl[kv * 88 + d] : (unsigned short)0;
        }
        *reinterpret_cast<us8*>(&out[d * 80 + seg * 8]) = v;
    }
}

// ---------------- O-proj: 256x128 pipelined, XCD swizzle (640 % 8 == 0) ----------------
__global__ __launch_bounds__(512) void gemm_o(
    const unsigned short* __restrict__ Ap, const unsigned short* __restrict__ Wt,
    const float* __restrict__ bias, float* __restrict__ Cp)
{
    __shared__ __align__(16) unsigned short smem[24576];   // 48 KB
    const int orig = blockIdx.x;
    const int wgid = (orig & 7) * 80 + (orig >> 3);
    gemm_pipe<true>(Ap, Wt, bias, Cp, 32768, 640, 640,
                    (wgid / 5) * 256, (wgid % 5) * 128, smem);
}

// ---------------- attention: per (128 q-rows, head, batch) ----------------
// LDS: P [2 waves][64][80] (20480 B) -> reused as O [128][80]. 8 blocks/CU.
__global__ __launch_bounds__(128) void attn_kernel(
    const unsigned short* __restrict__ Q,
    const unsigned short* __restrict__ Kp,   // [2464][640]
    const unsigned short* __restrict__ Vt,   // [256][80][80], kv 77..79 zeroed
    unsigned short* __restrict__ Oa)
{
    __shared__ __align__(16) unsigned short smem[10240];
    const int tid = threadIdx.x, lane = tid & 63, wave = tid >> 6;
    const int l15 = lane & 15, l4 = lane >> 4;
    const int qb = blockIdx.x * 128, h = blockIdx.y, b = blockIdx.z;
    const size_t qrow0 = (size_t)b * SQ_ + qb + wave * 64;
    const size_t kbase = (size_t)b * SKV_ * E_ + h * DH_;
    const size_t vbase = (size_t)(b * 8 + h) * 6400;

    bf16x8 aq[3][4];
#pragma unroll
    for (int ks = 0; ks < 3; ++ks) {
        const int d = ks * 32 + l4 * 8;
#pragma unroll
        for (int m = 0; m < 4; ++m)
            aq[ks][m] = (d < 80) ? lv8(&Q[(qrow0 + m * 16 + l15) * E_ + h * DH_ + d]) : zero8();
    }

    f32x4 accS[4][5];
#pragma unroll
    for (int m = 0; m < 4; ++m)
#pragma unroll
        for (int n = 0; n < 5; ++n)
#pragma unroll
            for (int i = 0; i < 4; ++i) accS[m][n][i] = 0.f;

#pragma unroll
    for (int ks = 0; ks < 3; ++ks) {
        const int d = ks * 32 + l4 * 8;
        bf16x8 bk[5];
#pragma unroll
        for (int n = 0; n < 5; ++n) {
            const int kv = n * 16 + l15;
            bk[n] = (kv < SKV_ && d < 80) ? lv8(&Kp[kbase + (size_t)kv * E_ + d]) : zero8();
        }
        __builtin_amdgcn_s_setprio(1);
#pragma unroll
        for (int n = 0; n < 5; ++n)
#pragma unroll
            for (int m = 0; m < 4; ++m)
                accS[m][n] = __builtin_amdgcn_mfma_f32_16x16x32_bf16(aq[ks][m], bk[n], accS[m][n], 0, 0, 0);
        __builtin_amdgcn_s_setprio(0);
    }

    unsigned short* Pw = smem + wave * 5120;   // [64][80]

    const float scale = 0.11180339887498949f; // 1/sqrt(80)
    float rs[4][4];
#pragma unroll
    for (int m = 0; m < 4; ++m) {
#pragma unroll
        for (int i = 0; i < 4; ++i) {
            float mx = -1e30f;
#pragma unroll
            for (int n = 0; n < 5; ++n) {
                float s = accS[m][n][i] * scale;
                if (n == 4 && l15 >= 13) s = -1e30f;   // kv = 64+l15 >= 77
                accS[m][n][i] = s;
                mx = fmaxf(mx, s);
            }
            mx = fmaxf(mx, __shfl_xor(mx, 1));
            mx = fmaxf(mx, __shfl_xor(mx, 2));
            mx = fmaxf(mx, __shfl_xor(mx, 4));
            mx = fmaxf(mx, __shfl_xor(mx, 8));
            float sum = 0.f;
            const int prow = m * 16 + l4 * 4 + i;
#pragma unroll
            for (int n = 0; n < 5; ++n) {
                float p = __expf(accS[m][n][i] - mx);
                sum += p;
                Pw[prow * 80 + n * 16 + l15] = f2b(p);
            }
            sum += __shfl_xor(sum, 1);
            sum += __shfl_xor(sum, 2);
            sum += __shfl_xor(sum, 4);
            sum += __shfl_xor(sum, 8);
            rs[m][i] = sum;
        }
    }

    f32x4 accO[4][5];
#pragma unroll
    for (int m = 0; m < 4; ++m)
#pragma unroll
        for (int n = 0; n < 5; ++n)
#pragma unroll
            for (int i = 0; i < 4; ++i) accO[m][n][i] = 0.f;

#pragma unroll
    for (int ks = 0; ks < 3; ++ks) {
        const int kv = ks * 32 + l4 * 8;
        bf16x8 ap[4], bv[5];
#pragma unroll
        for (int m = 0; m < 4; ++m)
            ap[m] = (ks < 2 || l4 < 2) ? lv8(&Pw[(m * 16 + l15) * 80 + ks * 32 + l4 * 8])
                                       : zero8();
#pragma unroll
        for (int n = 0; n < 5; ++n) {
            const int d = n * 16 + l15;   // always < 80
            bv[n] = (kv < 80) ? lv8(&Vt[vbase + (size_t)d * 80 + kv]) : zero8();
        }
        __builtin_amdgcn_s_setprio(1);
#pragma unroll
        for (int n = 0; n < 5; ++n)
#pragma unroll
            for (int m = 0; m < 4; ++m)
                accO[m][n] = __builtin_amdgcn_mfma_f32_16x16x32_bf16(ap[m], bv[n], accO[m][n], 0, 0, 0);
        __builtin_amdgcn_s_setprio(0);
    }

    __syncthreads();   // all waves done with P region; becomes O [128][80]
#pragma unroll
    for (int m = 0; m < 4; ++m) {
#pragma unroll
        for (int i = 0; i < 4; ++i) {
            const float inv = 1.f / rs[m][i];
            const int rl = wave * 64 + m * 16 + l4 * 4 + i;
#pragma unroll
            for (int n = 0; n < 5; ++n)
                smem[rl * 80 + n * 16 + l15] = f2b(accO[m][n][i] * inv);
        }
    }
    __syncthreads();
    const size_t obase = (size_t)b * SQ_ + qb;
    for (int idx = tid; idx < 1280; idx += 128) {
        int row = idx / 10, seg = idx % 10;
        *reinterpret_cast<us8*>(&Oa[(obase + row) * E_ + h * DH_ + seg * 8]) =
            *reinterpret_cast<us8*>(&smem[row * 80 + seg * 8]);
    }
}

extern "C" void kernel_launch(void* const* d_in, const int* in_sizes, int n_in,
                              void* d_out, int out_size, void* d_ws, size_t ws_size,
                              hipStream_t stream) {
    const float* x  = (const float*)d_in[0];
    const float* y  = (const float*)d_in[1];
    const float* Wq = (const float*)d_in[2];
    const float* bq = (const float*)d_in[3];
    const float* Wk = (const float*)d_in[4];
    const float* bk = (const float*)d_in[5];
    const float* Wv = (const float*)d_in[6];
    const float* bv = (const float*)d_in[7];
    const float* Wo = (const float*)d_in[8];
    const float* bo = (const float*)d_in[9];
    float* out = (float*)d_out;

    char* ws = (char*)d_ws;
    unsigned short* WqT = (unsigned short*)(ws + 0);         //  819,200 B
    unsigned short* WkT = (unsigned short*)(ws + 819200);    //  983,040 B
    unsigned short* WvT = (unsigned short*)(ws + 1802240);   //  983,040 B
    unsigned short* WoT = (unsigned short*)(ws + 2785280);   //  819,200 B
    unsigned short* Qb  = (unsigned short*)(ws + 3604480);   // 41,943,040 B
    unsigned short* Kb  = (unsigned short*)(ws + 45547520);  //  3,153,920 B
    unsigned short* Vb  = (unsigned short*)(ws + 48701440);  //  3,153,920 B
    unsigned short* Xb  = (unsigned short*)(ws + 51855360);  // 41,943,040 B
    unsigned short* Vtb = (unsigned short*)(ws + 93798400);  //  6,553,600 B
    unsigned short* Yb  = Vtb;  // aliases Vtb: Yb [2560][768] bf16 = 3,932,160 B,
                                // dead before vtrans writes Vtb
    // peak footprint: 100,352,000 B (proven available R13-R18)

    fused_prep<<<4048, 256, 0, stream>>>(Wq, WqT, Wo, WoT, Wk, WkT, Wv, WvT, x, Xb, y, Yb);
    fused_qkv<<<740, 512, 0, stream>>>(Xb, WqT, bq, Qb, Yb, WkT, bk, Kb, WvT, bv, Vb);
    vtrans_kernel<<<256, 256, 0, stream>>>(Vb, Vtb);
    attn_kernel<<<dim3(8, 8, 32), 128, 0, stream>>>(Qb, Kb, Vtb, Qb);
    gemm_o<<<640, 512, 0, stream>>>(Qb, WoT, bo, out);
}

// Round 20
// 154.273 us; speedup vs baseline: 1.0275x; 1.0275x over previous
//
#include <hip/hip_runtime.h>
#include <hip/hip_bf16.h>

typedef __bf16 bf16x8 __attribute__((ext_vector_type(8)));
typedef float f32x4 __attribute__((ext_vector_type(4)));
typedef unsigned short us8 __attribute__((ext_vector_type(8)));
typedef unsigned int u32x4 __attribute__((ext_vector_type(4)));

#define E_ 640
#define CD_ 768
#define B_ 32
#define SQ_ 1024
#define SKV_ 77
#define H_ 8
#define DH_ 80

typedef __attribute__((address_space(3))) unsigned int as3_u32;
typedef __attribute__((address_space(1))) const unsigned int as1_u32;

__device__ __forceinline__ void gload16(const unsigned short* g, unsigned short* l) {
    __builtin_amdgcn_global_load_lds((as1_u32*)g, (as3_u32*)l, 16, 0, 0);
}

__device__ __forceinline__ float b2f(unsigned short u) {
    unsigned int x = ((unsigned int)u) << 16;
    return __builtin_bit_cast(float, x);
}
__device__ __forceinline__ unsigned short f2b(float f) {
    unsigned int x = __builtin_bit_cast(unsigned int, f);
    x += 0x7fffu + ((x >> 16) & 1u);   // RNE
    return (unsigned short)(x >> 16);
}
__device__ __forceinline__ bf16x8 lv8(const unsigned short* p) {
    return __builtin_bit_cast(bf16x8, *reinterpret_cast<const us8*>(p));
}
__device__ __forceinline__ bf16x8 zero8() {
    us8 z = {0,0,0,0,0,0,0,0};
    return __builtin_bit_cast(bf16x8, z);
}
// 8 fp32 -> bf16x8 via v_cvt_pk_bf16_f32 (RNE)
__device__ __forceinline__ bf16x8 cvtpk8(f32x4 lo, f32x4 hi) {
    unsigned int w0, w1, w2, w3;
    asm("v_cvt_pk_bf16_f32 %0, %1, %2" : "=v"(w0) : "v"(lo[0]), "v"(lo[1]));
    asm("v_cvt_pk_bf16_f32 %0, %1, %2" : "=v"(w1) : "v"(lo[2]), "v"(lo[3]));
    asm("v_cvt_pk_bf16_f32 %0, %1, %2" : "=v"(w2) : "v"(hi[0]), "v"(hi[1]));
    asm("v_cvt_pk_bf16_f32 %0, %1, %2" : "=v"(w3) : "v"(hi[2]), "v"(hi[3]));
    u32x4 w = {w0, w1, w2, w3};
    return __builtin_bit_cast(bf16x8, w);
}
__device__ __forceinline__ us8 cvt8(const float* s) {
    f32x4 f0 = *reinterpret_cast<const f32x4*>(s);
    f32x4 f1 = *reinterpret_cast<const f32x4*>(s + 4);
    return __builtin_bit_cast(us8, cvtpk8(f0, f1));
}

// ---------------- fused prep: 4 weight transposes + x,y -> bf16 converts ----------------
__device__ __forceinline__ void transpose_body(
    const float* __restrict__ in, unsigned short* __restrict__ out,
    int K, int N, int bx, int by, unsigned short (*t)[33])
{
    const int tx = threadIdx.x & 31, ty = threadIdx.x >> 5;
    const int n0 = bx * 32, k0 = by * 32;
#pragma unroll
    for (int i = 0; i < 4; ++i)
        t[ty + 8*i][tx] = f2b(in[(size_t)(k0 + ty + 8*i) * N + n0 + tx]);
    __syncthreads();
#pragma unroll
    for (int i = 0; i < 4; ++i)
        out[(size_t)(n0 + ty + 8*i) * K + k0 + tx] = t[tx][ty + 8*i];
}

__global__ __launch_bounds__(256) void fused_prep(
    const float* __restrict__ Wq, unsigned short* __restrict__ WqT,
    const float* __restrict__ Wo, unsigned short* __restrict__ WoT,
    const float* __restrict__ Wk, unsigned short* __restrict__ WkT,
    const float* __restrict__ Wv, unsigned short* __restrict__ WvT,
    const float* __restrict__ x, unsigned short* __restrict__ Xb,
    const float* __restrict__ y, unsigned short* __restrict__ Yb)
{
    __shared__ unsigned short t[32][33];
    const int id = blockIdx.x;
    if (id < 800) {                         // Wq / Wo : [640][640]
        int z = id / 400, rem = id % 400;
        transpose_body(z ? Wo : Wq, z ? WoT : WqT, 640, 640, rem % 20, rem / 20, t);
    } else if (id < 1760) {                 // Wk / Wv : [768][640]
        int id2 = id - 800, z = id2 / 480, rem = id2 % 480;
        transpose_body(z ? Wv : Wk, z ? WvT : WkT, 768, 640, rem % 20, rem / 20, t);
    } else if (id < 3808) {                 // convert x: 2048 blocks, 2,621,440 x us8
        long i = (long)(id - 1760) * 256 + threadIdx.x;
        const long stride = 2048L * 256;
        for (const long n8 = 2621440L; i < n8; i += stride)
            *reinterpret_cast<us8*>(Xb + i * 8) = cvt8(x + i * 8);
    } else {                                // convert y: 240 blocks, 236,544 x us8
        long i = (long)(id - 3808) * 256 + threadIdx.x;
        const long stride = 240L * 256;
        for (const long n8 = 236544L; i < n8; i += stride)
            *reinterpret_cast<us8*>(Yb + i * 8) = cvt8(y + i * 8);
    }
}

// ======== pipelined 256x128 GEMM (bf16 A via global_load_lds, 512 threads) ========
// 8 waves in a 4x2 grid, each computing 64x64. 3-buffer K-loop, ONE raw
// s_barrier per K-step, counted vmcnt(3) (3 loads/stage, one stage in
// flight across the barrier). LDS/buffer: As 256x32 (16KB) + Ws 128x32 (8KB).
// A rows [m0, m0+256) must be readable; C stores masked by grow < M.
template<bool CF32>
__device__ __forceinline__ void gemm_pipe(
    const unsigned short* __restrict__ A,
    const unsigned short* __restrict__ Wt,
    const float* __restrict__ bias,
    void* __restrict__ Cp,
    int M, int K, int ldc, int m0, int n0,
    unsigned short* smem)    // >= 36864 shorts (72 KB)
{
    const int tid = threadIdx.x, lane = tid & 63, wave = tid >> 6;
    const int wr = (wave >> 1) << 6;          // 0,64,128,192
    const int wc = (wave & 1) << 6;           // 0,64
    const int l15 = lane & 15, l4 = lane >> 4;
    const int sgz = (tid >> 3) & 3;
    const int srd = (l15 >> 1) & 3;
    const int rdo = (l4 ^ srd) << 3;

    const unsigned short* gW0 = Wt + (size_t)(n0 + (tid >> 2)) * K + (((tid & 3) ^ sgz) << 3);
    const unsigned short* gA0 = A + (size_t)(m0 + (tid >> 2)) * K + (((tid & 3) ^ sgz) << 3);
    const unsigned short* gA1 = A + (size_t)(m0 + (tid >> 2) + 128) * K + (((tid & 3) ^ sgz) << 3);

    f32x4 acc[4][4];
#pragma unroll
    for (int m = 0; m < 4; ++m)
#pragma unroll
        for (int n = 0; n < 4; ++n)
#pragma unroll
            for (int i = 0; i < 4; ++i) acc[m][n][i] = 0.f;

    auto STAGE = [&](int buf) {
        unsigned short* As = smem + buf * 12288;
        unsigned short* Ws = As + 8192;
        gload16(gA0, As + tid * 8);
        gload16(gA1, As + (tid + 512) * 8);
        gload16(gW0, Ws + tid * 8);
        gA0 += 32; gA1 += 32; gW0 += 32;
    };
    auto COMPUTE = [&](int buf) {
        const unsigned short* As = smem + buf * 12288;
        const unsigned short* Ws = As + 8192;
        bf16x8 a[4], b[4];
#pragma unroll
        for (int m = 0; m < 4; ++m)
            a[m] = lv8(&As[(wr + m * 16 + l15) * 32 + rdo]);
#pragma unroll
        for (int n = 0; n < 4; ++n)
            b[n] = lv8(&Ws[(wc + n * 16 + l15) * 32 + rdo]);
        __builtin_amdgcn_s_setprio(1);
#pragma unroll
        for (int m = 0; m < 4; ++m)
#pragma unroll
            for (int n = 0; n < 4; ++n)
                acc[m][n] = __builtin_amdgcn_mfma_f32_16x16x32_bf16(a[m], b[n], acc[m][n], 0, 0, 0);
        __builtin_amdgcn_s_setprio(0);
    };

    const int nk = K >> 5;   // 20 or 24: >= 3
    STAGE(0);
    STAGE(1);
    for (int t = 0; t < nk; ++t) {
        if (t == nk - 1) { asm volatile("s_waitcnt vmcnt(0)" ::: "memory"); }
        else             { asm volatile("s_waitcnt vmcnt(3)" ::: "memory"); }
        __builtin_amdgcn_sched_barrier(0);
        __builtin_amdgcn_s_barrier();
        COMPUTE(t % 3);
        if (t + 2 < nk) STAGE((t + 2) % 3);
    }

    float bs[4];
#pragma unroll
    for (int n = 0; n < 4; ++n) bs[n] = bias[n0 + wc + n * 16 + l15];

    if constexpr (CF32) {
        // fp32 epilogue: two 128-row passes, 128x128 f32 tile (64 KB) in LDS
        float* C = (float*)Cp;
        float* fs = (float*)smem;
#pragma unroll
        for (int p = 0; p < 2; ++p) {
            __syncthreads();
            if ((wr >> 7) == p) {
                const int lr0 = (wr & 64);
#pragma unroll
                for (int m = 0; m < 4; ++m)
#pragma unroll
                    for (int n = 0; n < 4; ++n)
#pragma unroll
                        for (int i = 0; i < 4; ++i)
                            fs[(lr0 + m * 16 + l4 * 4 + i) * 128 + wc + n * 16 + l15] =
                                acc[m][n][i] + bs[n];
            }
            __syncthreads();
#pragma unroll
            for (int r = 0; r < 8; ++r) {
                const int off = (r * 512 + tid) * 4;
                const int row = off >> 7, col = off & 127;
                const int grow = m0 + p * 128 + row;
                if (grow < M)
                    *reinterpret_cast<f32x4*>(&C[(size_t)grow * ldc + n0 + col]) =
                        *reinterpret_cast<const f32x4*>(&fs[off]);
            }
        }
    } else {
        // bf16 epilogue: full 256x128 bf16 tile (64 KB) in LDS, one pass
        unsigned short* C = (unsigned short*)Cp;
        __syncthreads();
#pragma unroll
        for (int m = 0; m < 4; ++m)
#pragma unroll
            for (int n = 0; n < 4; ++n)
#pragma unroll
                for (int i = 0; i < 4; ++i)
                    smem[(wr + m * 16 + l4 * 4 + i) * 128 + wc + n * 16 + l15] =
                        f2b(acc[m][n][i] + bs[n]);
        __syncthreads();
#pragma unroll
        for (int r = 0; r < 8; ++r) {
            const int off = (r * 512 + tid) * 8;
            const int row = off >> 7, col = off & 127;
            const int grow = m0 + row;
            if (grow < M)
                *reinterpret_cast<us8*>(&C[(size_t)grow * ldc + n0 + col]) =
                    *reinterpret_cast<us8*>(&smem[off]);
        }
    }
}

// ---------------- fused QKV: all three projections via 256x128 gemm_pipe ----------------
// blocks [0,50): K; [50,100): V (Yb padded to 2560 rows); [100,740): Q (XCD swizzle)
__global__ __launch_bounds__(512) void fused_qkv(
    const unsigned short* __restrict__ Xb, const unsigned short* __restrict__ WqT,
    const float* __restrict__ bq, unsigned short* __restrict__ Qb,
    const unsigned short* __restrict__ Yb,
    const unsigned short* __restrict__ WkT, const float* __restrict__ bk2, unsigned short* __restrict__ Kb,
    const unsigned short* __restrict__ WvT, const float* __restrict__ bv2, unsigned short* __restrict__ Vb)
{
    __shared__ __align__(16) unsigned short smem[36864];   // 72 KB
    const int id = blockIdx.x;
    if (id < 100) {
        int z = id / 50, rem = id % 50;
        int m0 = (rem / 5) * 256, n0 = (rem % 5) * 128;    // m0 up to 2304
        if (z == 0) gemm_pipe<false>(Yb, WkT, bk2, Kb, 2464, 768, 640, m0, n0, smem);
        else        gemm_pipe<false>(Yb, WvT, bv2, Vb, 2464, 768, 640, m0, n0, smem);
    } else {
        int orig = id - 100;                       // 0..639, 640 % 8 == 0
        int wgid = (orig & 7) * 80 + (orig >> 3);  // XCD-chunked bijection
        int m0 = (wgid / 5) * 256, n0 = (wgid % 5) * 128;
        gemm_pipe<false>(Xb, WqT, bq, Qb, 32768, 640, 640, m0, n0, smem);
    }
}

// ---------------- vtrans: Vb [32*77][640] -> Vt [b*8+h][80][80] (kv 77..79 zeroed) ----------------
__global__ __launch_bounds__(256) void vtrans_kernel(
    const unsigned short* __restrict__ Vb, unsigned short* __restrict__ Vt)
{
    __shared__ unsigned short Vl[77 * 88 + 8];
    const int r = blockIdx.x, b = r >> 3, h = r & 7;
    const int tid = threadIdx.x;
    for (int idx = tid; idx < 770; idx += 256) {
        int kv = idx / 10, seg = idx % 10;
        *reinterpret_cast<us8*>(&Vl[kv * 88 + seg * 8]) =
            *reinterpret_cast<const us8*>(&Vb[(size_t)(b * 77 + kv) * 640 + h * 80 + seg * 8]);
    }
    __syncthreads();
    unsigned short* out = Vt + (size_t)(b * 8 + h) * 6400;
    for (int idx = tid; idx < 800; idx += 256) {
        int d = idx / 10, seg = idx % 10;
        us8 v;
#pragma unroll
        for (int j = 0; j < 8; ++j) {
            int kv = seg * 8 + j;
            v[j] = (kv < 77) ? Vl[kv * 88 + d] : (unsigned short)0;
        }
        *reinterpret_cast<us8*>(&out[d * 80 + seg * 8]) = v;
    }
}

// ---------------- O-proj: 256x128 pipelined, XCD swizzle (640 % 8 == 0) ----------------
__global__ __launch_bounds__(512) void gemm_o(
    const unsigned short* __restrict__ Ap, const unsigned short* __restrict__ Wt,
    const float* __restrict__ bias, float* __restrict__ Cp)
{
    __shared__ __align__(16) unsigned short smem[36864];   // 72 KB
    const int orig = blockIdx.x;
    const int wgid = (orig & 7) * 80 + (orig >> 3);
    gemm_pipe<true>(Ap, Wt, bias, Cp, 32768, 640, 640,
                    (wgid / 5) * 256, (wgid % 5) * 128, smem);
}

// ---------------- attention: per (128 q-rows, head, batch) ----------------
__global__ __launch_bounds__(128) void attn_kernel(
    const unsigned short* __restrict__ Q,
    const unsigned short* __restrict__ Kp,   // [2464][640]
    const unsigned short* __restrict__ Vt,   // [256][80][80], kv 77..79 zeroed
    unsigned short* __restrict__ Oa)
{
    __shared__ __align__(16) unsigned short smem[11272];  // P [2][64][88] -> O [128][80]
    const int tid = threadIdx.x, lane = tid & 63, wave = tid >> 6;
    const int l15 = lane & 15, l4 = lane >> 4;
    const int qb = blockIdx.x * 128, h = blockIdx.y, b = blockIdx.z;
    const size_t qrow0 = (size_t)b * SQ_ + qb + wave * 64;
    const size_t kbase = (size_t)b * SKV_ * E_ + h * DH_;
    const size_t vbase = (size_t)(b * 8 + h) * 6400;

    bf16x8 aq[3][4];
#pragma unroll
    for (int ks = 0; ks < 3; ++ks) {
        const int d = ks * 32 + l4 * 8;
#pragma unroll
        for (int m = 0; m < 4; ++m)
            aq[ks][m] = (d < 80) ? lv8(&Q[(qrow0 + m * 16 + l15) * E_ + h * DH_ + d]) : zero8();
    }

    f32x4 accS[4][5];
#pragma unroll
    for (int m = 0; m < 4; ++m)
#pragma unroll
        for (int n = 0; n < 5; ++n)
#pragma unroll
            for (int i = 0; i < 4; ++i) accS[m][n][i] = 0.f;

#pragma unroll
    for (int ks = 0; ks < 3; ++ks) {
        const int d = ks * 32 + l4 * 8;
        bf16x8 bk[5];
#pragma unroll
        for (int n = 0; n < 5; ++n) {
            const int kv = n * 16 + l15;
            bk[n] = (kv < SKV_ && d < 80) ? lv8(&Kp[kbase + (size_t)kv * E_ + d]) : zero8();
        }
        __builtin_amdgcn_s_setprio(1);
#pragma unroll
        for (int n = 0; n < 5; ++n)
#pragma unroll
            for (int m = 0; m < 4; ++m)
                accS[m][n] = __builtin_amdgcn_mfma_f32_16x16x32_bf16(aq[ks][m], bk[n], accS[m][n], 0, 0, 0);
        __builtin_amdgcn_s_setprio(0);
    }

    unsigned short* Pw = smem + wave * 5632;   // [64][88]

    const float scale = 0.11180339887498949f; // 1/sqrt(80)
    float rs[4][4];
#pragma unroll
    for (int m = 0; m < 4; ++m) {
#pragma unroll
        for (int i = 0; i < 4; ++i) {
            float mx = -1e30f;
#pragma unroll
            for (int n = 0; n < 5; ++n) {
                float s = accS[m][n][i] * scale;
                if (n == 4 && l15 >= 13) s = -1e30f;   // kv = 64+l15 >= 77
                accS[m][n][i] = s;
                mx = fmaxf(mx, s);
            }
            mx = fmaxf(mx, __shfl_xor(mx, 1));
            mx = fmaxf(mx, __shfl_xor(mx, 2));
            mx = fmaxf(mx, __shfl_xor(mx, 4));
            mx = fmaxf(mx, __shfl_xor(mx, 8));
            float sum = 0.f;
            const int prow = m * 16 + l4 * 4 + i;
#pragma unroll
            for (int n = 0; n < 5; ++n) {
                float p = __expf(accS[m][n][i] - mx);
                sum += p;
                Pw[prow * 88 + n * 16 + l15] = f2b(p);
            }
            sum += __shfl_xor(sum, 1);
            sum += __shfl_xor(sum, 2);
            sum += __shfl_xor(sum, 4);
            sum += __shfl_xor(sum, 8);
            rs[m][i] = sum;
        }
    }

    f32x4 accO[4][5];
#pragma unroll
    for (int m = 0; m < 4; ++m)
#pragma unroll
        for (int n = 0; n < 5; ++n)
#pragma unroll
            for (int i = 0; i < 4; ++i) accO[m][n][i] = 0.f;

#pragma unroll
    for (int ks = 0; ks < 3; ++ks) {
        const int kv = ks * 32 + l4 * 8;
        bf16x8 ap[4], bv[5];
#pragma unroll
        for (int m = 0; m < 4; ++m)
            ap[m] = (ks < 2 || l4 < 2) ? lv8(&Pw[(m * 16 + l15) * 88 + ks * 32 + l4 * 8])
                                       : zero8();
#pragma unroll
        for (int n = 0; n < 5; ++n) {
            const int d = n * 16 + l15;   // always < 80
            bv[n] = (kv < 80) ? lv8(&Vt[vbase + (size_t)d * 80 + kv]) : zero8();
        }
        __builtin_amdgcn_s_setprio(1);
#pragma unroll
        for (int n = 0; n < 5; ++n)
#pragma unroll
            for (int m = 0; m < 4; ++m)
                accO[m][n] = __builtin_amdgcn_mfma_f32_16x16x32_bf16(ap[m], bv[n], accO[m][n], 0, 0, 0);
        __builtin_amdgcn_s_setprio(0);
    }

    __syncthreads();   // all waves done with P region; becomes O [128][80]
#pragma unroll
    for (int m = 0; m < 4; ++m) {
#pragma unroll
        for (int i = 0; i < 4; ++i) {
            const float inv = 1.f / rs[m][i];
            const int rl = wave * 64 + m * 16 + l4 * 4 + i;
#pragma unroll
            for (int n = 0; n < 5; ++n)
                smem[rl * 80 + n * 16 + l15] = f2b(accO[m][n][i] * inv);
        }
    }
    __syncthreads();
    const size_t obase = (size_t)b * SQ_ + qb;
    for (int idx = tid; idx < 1280; idx += 128) {
        int row = idx / 10, seg = idx % 10;
        *reinterpret_cast<us8*>(&Oa[(obase + row) * E_ + h * DH_ + seg * 8]) =
            *reinterpret_cast<us8*>(&smem[row * 80 + seg * 8]);
    }
}

extern "C" void kernel_launch(void* const* d_in, const int* in_sizes, int n_in,
                              void* d_out, int out_size, void* d_ws, size_t ws_size,
                              hipStream_t stream) {
    const float* x  = (const float*)d_in[0];
    const float* y  = (const float*)d_in[1];
    const float* Wq = (const float*)d_in[2];
    const float* bq = (const float*)d_in[3];
    const float* Wk = (const float*)d_in[4];
    const float* bk = (const float*)d_in[5];
    const float* Wv = (const float*)d_in[6];
    const float* bv = (const float*)d_in[7];
    const float* Wo = (const float*)d_in[8];
    const float* bo = (const float*)d_in[9];
    float* out = (float*)d_out;

    char* ws = (char*)d_ws;
    unsigned short* WqT = (unsigned short*)(ws + 0);         //  819,200 B
    unsigned short* WkT = (unsigned short*)(ws + 819200);    //  983,040 B
    unsigned short* WvT = (unsigned short*)(ws + 1802240);   //  983,040 B
    unsigned short* WoT = (unsigned short*)(ws + 2785280);   //  819,200 B
    unsigned short* Qb  = (unsigned short*)(ws + 3604480);   // 41,943,040 B
    unsigned short* Kb  = (unsigned short*)(ws + 45547520);  //  3,153,920 B
    unsigned short* Vb  = (unsigned short*)(ws + 48701440);  //  3,153,920 B
    unsigned short* Xb  = (unsigned short*)(ws + 51855360);  // 41,943,040 B
    unsigned short* Vtb = (unsigned short*)(ws + 93798400);  //  6,553,600 B
    unsigned short* Yb  = Vtb;  // aliases Vtb: Yb [2560][768] bf16 = 3,932,160 B,
                                // dead before vtrans writes Vtb
    // peak footprint: 100,352,000 B (proven available R13-R19)

    fused_prep<<<4048, 256, 0, stream>>>(Wq, WqT, Wo, WoT, Wk, WkT, Wv, WvT, x, Xb, y, Yb);
    fused_qkv<<<740, 512, 0, stream>>>(Xb, WqT, bq, Qb, Yb, WkT, bk, Kb, WvT, bv, Vb);
    vtrans_kernel<<<256, 256, 0, stream>>>(Vb, Vtb);
    attn_kernel<<<dim3(8, 8, 32), 128, 0, stream>>>(Qb, Kb, Vtb, Qb);
    gemm_o<<<640, 512, 0, stream>>>(Qb, WoT, bo, out);
}